// Round 4
// baseline (199.579 us; speedup 1.0000x reference)
//
#include <hip/hip_runtime.h>

// ---------------- problem constants ----------------
#define LL 2048
#define BB 16
#define HH 512
#define PP 256
#define MM (LL*BB)   // 32768 rows
#define NN 512       // all GEMMs: N=512
#define KK 512       // all GEMMs: K=512
#define NC 64        // scan chunks
#define CLEN 32      // chunk length (NC*CLEN == LL)
#define NKT (KK/64)  // 8 K-tiles of 64

typedef __bf16 bf16x8 __attribute__((ext_vector_type(8)));
typedef float  f32x4  __attribute__((ext_vector_type(4)));

__device__ __forceinline__ unsigned short f2bf(float f) {
  unsigned u = __builtin_bit_cast(unsigned, f);
  u = (u + 0x7fffu + ((u >> 16) & 1u)) >> 16;   // RNE
  return (unsigned short)u;
}
__device__ __forceinline__ float bf2f(unsigned short s) {
  unsigned u = ((unsigned)s) << 16;
  return __builtin_bit_cast(float, u);
}

// ---------------- dtype detection for `d` ----------------
__global__ void detect_kernel(const unsigned int* __restrict__ dw, int* __restrict__ flag) {
  __shared__ int sInt, sFloat;
  if (threadIdx.x == 0) { sInt = 1; sFloat = 1; }
  __syncthreads();
  int allInt = 1, allFloat = 1;
  for (int i = threadIdx.x; i < 8192; i += 256) {
    unsigned v = dw[i];
    if (v > 1u) allInt = 0;
    if (v != 0u && v != 0x3f800000u) allFloat = 0;
  }
  if (!allInt) atomicAnd(&sInt, 0);
  if (!allFloat) atomicAnd(&sFloat, 0);
  __syncthreads();
  if (threadIdx.x == 0) *flag = sInt ? 0 : (sFloat ? 1 : 2);
}

__device__ __forceinline__ float keep_val(const void* d, int flag, int idx) {
  if (flag == 0) return 1.f - (float)((const int*)d)[idx];
  if (flag == 1) return 1.f - ((const float*)d)[idx];
  return 1.f - (float)((const unsigned char*)d)[idx];
}

// ---------------- weight precompute ----------------
__global__ void precompute_kernel(
    const float* __restrict__ Lre, const float* __restrict__ Lim,
    const float* __restrict__ Bre, const float* __restrict__ Bim,
    const float* __restrict__ Cre, const float* __restrict__ Cim,
    const float* __restrict__ lstep, const float* __restrict__ w2,
    unsigned short* __restrict__ W1t, unsigned short* __restrict__ W2t,
    unsigned short* __restrict__ W3t, float* __restrict__ lam_re,
    float* __restrict__ lam_im) {
  int t = blockIdx.x * 256 + threadIdx.x;   // 0..262143
  int k = t & (KK - 1);
  int n = t >> 9;
  {
    int p = n & (PP - 1);
    float lr = Lre[p], li = Lim[p];
    float st = expf(lstep[p]);
    float er = expf(lr * st);
    float ang = li * st;
    float lbr = er * cosf(ang), lbi = er * sinf(ang);
    float den = lr * lr + li * li;
    float wr = ((lbr - 1.f) * lr + lbi * li) / den;
    float wi = (lbi * lr - (lbr - 1.f) * li) / den;
    float br = Bre[p * HH + k], bi = Bim[p * HH + k];
    float v = (n < PP) ? (wr * br - wi * bi) : (wr * bi + wi * br);
    W1t[(size_t)n * KK + k] = f2bf(v);
  }
  {
    float v = (k < PP) ? (2.f * Cre[n * PP + k]) : (-2.f * Cim[n * PP + (k - PP)]);
    W2t[(size_t)n * KK + k] = f2bf(v);
  }
  W3t[(size_t)n * KK + k] = f2bf(w2[(size_t)k * HH + n]);
  if (t < PP) {
    float lr = Lre[t], li = Lim[t];
    float st = expf(lstep[t]);
    float er = expf(lr * st);
    float ang = li * st;
    lam_re[t] = er * cosf(ang);
    lam_im[t] = er * sinf(ang);
  }
}

// ---------------- LayerNorm (1 wave per 512-wide row, 4 rows/block) -------------
__global__ void ln1_kernel(const float* __restrict__ x, const float* __restrict__ sc,
                           const float* __restrict__ bs, unsigned short* __restrict__ xn) {
  int row = blockIdx.x * 4 + (threadIdx.x >> 6);
  int lane = threadIdx.x & 63;
  const float4* xr = (const float4*)(x + (size_t)row * HH) + lane * 2;
  float4 a = xr[0], b = xr[1];
  float s = (a.x + a.y) + (a.z + a.w) + (b.x + b.y) + (b.z + b.w);
  float q = a.x * a.x + a.y * a.y + a.z * a.z + a.w * a.w +
            b.x * b.x + b.y * b.y + b.z * b.z + b.w * b.w;
#pragma unroll
  for (int off = 32; off; off >>= 1) { s += __shfl_xor(s, off); q += __shfl_xor(q, off); }
  float mean = s * (1.f / HH);
  float var = fmaxf(q * (1.f / HH) - mean * mean, 0.f);
  float rstd = rsqrtf(var + 1e-6f);
  const float4* scp = (const float4*)sc + lane * 2;
  const float4* bsp = (const float4*)bs + lane * 2;
  float4 s0 = scp[0], s1 = scp[1], b0 = bsp[0], b1 = bsp[1];
  unsigned short o[8];
  o[0] = f2bf((a.x - mean) * rstd * s0.x + b0.x);
  o[1] = f2bf((a.y - mean) * rstd * s0.y + b0.y);
  o[2] = f2bf((a.z - mean) * rstd * s0.z + b0.z);
  o[3] = f2bf((a.w - mean) * rstd * s0.w + b0.w);
  o[4] = f2bf((b.x - mean) * rstd * s1.x + b1.x);
  o[5] = f2bf((b.y - mean) * rstd * s1.y + b1.y);
  o[6] = f2bf((b.z - mean) * rstd * s1.z + b1.z);
  o[7] = f2bf((b.w - mean) * rstd * s1.w + b1.w);
  uint4 pk;
  pk.x = o[0] | ((unsigned)o[1] << 16);
  pk.y = o[2] | ((unsigned)o[3] << 16);
  pk.z = o[4] | ((unsigned)o[5] << 16);
  pk.w = o[6] | ((unsigned)o[7] << 16);
  *((uint4*)(xn + (size_t)row * HH) + lane) = pk;
}

// LN + GELU: reads ys (bf16), writes y (bf16) and x1 = gelu(y) (bf16)
__global__ void ln2_kernel(const unsigned short* __restrict__ ys, const float* __restrict__ sc,
                           const float* __restrict__ bs, unsigned short* __restrict__ y,
                           unsigned short* __restrict__ x1) {
  int row = blockIdx.x * 4 + (threadIdx.x >> 6);
  int lane = threadIdx.x & 63;
  uint4 pin = *((const uint4*)(ys + (size_t)row * HH) + lane);
  float v[8];
  v[0] = bf2f((unsigned short)(pin.x & 0xffff)); v[1] = bf2f((unsigned short)(pin.x >> 16));
  v[2] = bf2f((unsigned short)(pin.y & 0xffff)); v[3] = bf2f((unsigned short)(pin.y >> 16));
  v[4] = bf2f((unsigned short)(pin.z & 0xffff)); v[5] = bf2f((unsigned short)(pin.z >> 16));
  v[6] = bf2f((unsigned short)(pin.w & 0xffff)); v[7] = bf2f((unsigned short)(pin.w >> 16));
  float s = 0.f, q = 0.f;
#pragma unroll
  for (int j = 0; j < 8; j++) { s += v[j]; q += v[j] * v[j]; }
#pragma unroll
  for (int off = 32; off; off >>= 1) { s += __shfl_xor(s, off); q += __shfl_xor(q, off); }
  float mean = s * (1.f / HH);
  float var = fmaxf(q * (1.f / HH) - mean * mean, 0.f);
  float rstd = rsqrtf(var + 1e-6f);
  const float4* scp = (const float4*)sc + lane * 2;
  const float4* bsp = (const float4*)bs + lane * 2;
  float4 s0 = scp[0], s1 = scp[1], b0 = bsp[0], b1 = bsp[1];
  float scv[8] = { s0.x, s0.y, s0.z, s0.w, s1.x, s1.y, s1.z, s1.w };
  float bsv[8] = { b0.x, b0.y, b0.z, b0.w, b1.x, b1.y, b1.z, b1.w };
  unsigned short oy[8], og[8];
#pragma unroll
  for (int j = 0; j < 8; j++) {
    float yv = (v[j] - mean) * rstd * scv[j] + bsv[j];
    oy[j] = f2bf(yv);
    float g = 0.5f * yv * (1.f + tanhf(0.7978845608f * (yv + 0.044715f * yv * yv * yv)));
    og[j] = f2bf(g);
  }
  uint4 py, pg;
  py.x = oy[0] | ((unsigned)oy[1] << 16); py.y = oy[2] | ((unsigned)oy[3] << 16);
  py.z = oy[4] | ((unsigned)oy[5] << 16); py.w = oy[6] | ((unsigned)oy[7] << 16);
  pg.x = og[0] | ((unsigned)og[1] << 16); pg.y = og[2] | ((unsigned)og[3] << 16);
  pg.z = og[4] | ((unsigned)og[5] << 16); pg.w = og[6] | ((unsigned)og[7] << 16);
  *((uint4*)(y  + (size_t)row * HH) + lane) = py;
  *((uint4*)(x1 + (size_t)row * HH) + lane) = pg;
}

// ---------------- 256x256 8-phase bf16 MFMA GEMM (T3+T4+T5, k-half swizzled LDS) ----
// C[m,n] = sum_k A[m,k] * Wt[n,k].  512 thr = 8 waves (2M x 4N), per-wave C 128x64.
// LDS [2 buf][2 kh][256 rows][32 k] bf16 per matrix (64KB each, 128KB total).
// Chunk swizzle: 16B-chunk c stored at slot c ^ ((row>>1)&3)  (2-way residual = free).
// Stage: linear global_load_lds dest + inverse-swizzled global source (rule #21).
// Schedule per iter (tiles t0=2j buf0, t1=2j+1 buf1), vmcnt(8) at even-phase ends:
//  ph1 c(0,ks0,fg0) s A-kh1(2j+1)   ph5 c(1,ks0,fg0) s A-kh1(2j+2)
//  ph2 c(0,ks0,fg1) s B-kh1(2j+1)V  ph6 c(1,ks0,fg1) s B-kh1(2j+2)V
//  ph3 c(0,ks1,fg0) s A-kh0(2j+2)   ph7 c(1,ks1,fg0) s A-kh0(2j+3)
//  ph4 c(0,ks1,fg1) s B-kh0(2j+2)V  ph8 c(1,ks1,fg1) s B-kh0(2j+3)V
template <int EPI>
__global__ __launch_bounds__(512, 2) void gemm_kernel(
    const unsigned short* __restrict__ A, const unsigned short* __restrict__ Wt,
    void* __restrict__ Cout, const float* __restrict__ Dvec,
    const unsigned short* __restrict__ aux16, const float* __restrict__ skip) {
  extern __shared__ unsigned short smem[];   // [0,32768): A   [32768,65536): B  (elements)
  const int tid = threadIdx.x;
  const int w = tid >> 6, lane = tid & 63;
  const int wr = w >> 2, wc = w & 3;         // 2 x 4 wave grid
  const int l15 = lane & 15, g16 = lane >> 4;
  // 256 blocks: xcd = wgid&7; XCD k owns m-tiles [k*16,(k+1)*16); n-pair adjacent.
  const int wgid = blockIdx.x;
  const int xcd = wgid & 7, bidx = wgid >> 3;       // bidx 0..31
  const int m0 = (xcd * 16 + (bidx >> 1)) * 256;
  const int n0 = (bidx & 1) * 256;

  // staging geometry: half-tile = 256 rows x 32 k = 1024 slots of 16B; 2 sweeps/thread
  const int rS = tid >> 2;                           // sweep-0 row (sweep1 = +128)
  const int cgS = (tid & 3) ^ ((rS >> 1) & 3);       // inverse-swizzled source chunk

  auto stageA = [&](int buf, int kh, int kt) {
    const unsigned short* gp = A + (size_t)(m0 + rS) * KK + kt * 64 + kh * 32 + cgS * 8;
    unsigned short* dp = smem + buf * 16384 + kh * 8192 + (w * 64) * 8;
    __builtin_amdgcn_global_load_lds((const __attribute__((address_space(1))) void*)gp,
                                     (__attribute__((address_space(3))) void*)dp, 16, 0, 0);
    __builtin_amdgcn_global_load_lds(
        (const __attribute__((address_space(1))) void*)(gp + (size_t)128 * KK),
        (__attribute__((address_space(3))) void*)(dp + 512 * 8), 16, 0, 0);
  };
  auto stageB = [&](int buf, int kh, int kt) {
    const unsigned short* gp = Wt + (size_t)(n0 + rS) * KK + kt * 64 + kh * 32 + cgS * 8;
    unsigned short* dp = smem + 32768 + buf * 16384 + kh * 8192 + (w * 64) * 8;
    __builtin_amdgcn_global_load_lds((const __attribute__((address_space(1))) void*)gp,
                                     (__attribute__((address_space(3))) void*)dp, 16, 0, 0);
    __builtin_amdgcn_global_load_lds(
        (const __attribute__((address_space(1))) void*)(gp + (size_t)128 * KK),
        (__attribute__((address_space(3))) void*)(dp + 512 * 8), 16, 0, 0);
  };
  auto readA = [&](int buf, int ks, int fm) -> bf16x8 {
    int row = wr * 128 + fm * 16 + l15;
    int ch = g16 ^ ((row >> 1) & 3);
    return *(const bf16x8*)(smem + buf * 16384 + ks * 8192 + row * 32 + ch * 8);
  };
  auto readB = [&](int buf, int ks, int fn) -> bf16x8 {
    int row = wc * 64 + fn * 16 + l15;
    int ch = g16 ^ ((row >> 1) & 3);
    return *(const bf16x8*)(smem + 32768 + buf * 16384 + ks * 8192 + row * 32 + ch * 8);
  };

  f32x4 acc[8][4];
#pragma unroll
  for (int i = 0; i < 8; i++)
#pragma unroll
    for (int j = 0; j < 4; j++) acc[i][j] = (f32x4){0.f, 0.f, 0.f, 0.f};
  bf16x8 bF[4];

#define PHASE(CB, KS, FG, STAGE_STMT, DO_VM)                                    \
  {                                                                             \
    bf16x8 aF[4];                                                               \
    _Pragma("unroll") for (int fi = 0; fi < 4; fi++)                            \
        aF[fi] = readA(CB, KS, (FG)*4 + fi);                                    \
    if ((FG) == 0) {                                                            \
      _Pragma("unroll") for (int fi = 0; fi < 4; fi++) bF[fi] = readB(CB, KS, fi); \
    }                                                                           \
    STAGE_STMT;                                                                 \
    __builtin_amdgcn_s_barrier();                                               \
    asm volatile("s_waitcnt lgkmcnt(0)" ::: "memory");                          \
    __builtin_amdgcn_sched_barrier(0);                                          \
    __builtin_amdgcn_s_setprio(1);                                              \
    _Pragma("unroll") for (int fi = 0; fi < 4; fi++)                            \
      _Pragma("unroll") for (int fj = 0; fj < 4; fj++)                          \
        acc[(FG)*4 + fi][fj] = __builtin_amdgcn_mfma_f32_16x16x32_bf16(         \
            aF[fi], bF[fj], acc[(FG)*4 + fi][fj], 0, 0, 0);                     \
    __builtin_amdgcn_s_setprio(0);                                              \
    if (DO_VM) asm volatile("s_waitcnt vmcnt(8)" ::: "memory");                 \
    __builtin_amdgcn_s_barrier();                                               \
  }

  // prologue: tile0 (4 halves) + tile1 kh0 (2 halves) = 12 loads; allow last 8 in flight
  stageA(0, 0, 0); stageB(0, 0, 0);
  stageA(0, 1, 0); stageB(0, 1, 0);
  stageA(1, 0, 1); stageB(1, 0, 1);
  asm volatile("s_waitcnt vmcnt(8)" ::: "memory");
  __builtin_amdgcn_s_barrier();

  for (int j = 0; j < NKT / 2; ++j) {
    const int t1 = 2 * j + 1;
    const int t2 = (2 * j + 2 < NKT) ? 2 * j + 2 : NKT - 1;
    const int t3 = (2 * j + 3 < NKT) ? 2 * j + 3 : NKT - 1;
    const bool s2 = (2 * j + 2) < NKT, s3 = (2 * j + 3) < NKT;
    PHASE(0, 0, 0, { stageA(1, 1, t1); }, false);            // ph1
    PHASE(0, 0, 1, { stageB(1, 1, t1); }, true);             // ph2
    PHASE(0, 1, 0, { if (s2) stageA(0, 0, t2); }, false);    // ph3
    PHASE(0, 1, 1, { if (s2) stageB(0, 0, t2); }, true);     // ph4
    PHASE(1, 0, 0, { if (s2) stageA(0, 1, t2); }, false);    // ph5
    PHASE(1, 0, 1, { if (s2) stageB(0, 1, t2); }, true);     // ph6
    PHASE(1, 1, 0, { if (s3) stageA(1, 0, t3); }, false);    // ph7
    PHASE(1, 1, 1, { if (s3) stageB(1, 0, t3); }, true);     // ph8
  }
#undef PHASE

  // epilogue: C/D layout col=lane&15, row=(lane>>4)*4+j  [m89-verified]
  const int lr4 = g16 * 4;
#pragma unroll
  for (int fm = 0; fm < 8; fm++) {
    int rowb = m0 + wr * 128 + fm * 16 + lr4;
#pragma unroll
    for (int fn = 0; fn < 4; fn++) {
      int col = n0 + wc * 64 + fn * 16 + l15;
#pragma unroll
      for (int jj = 0; jj < 4; jj++) {
        size_t idxo = (size_t)(rowb + jj) * NN + col;
        float v = acc[fm][fn][jj];
        if (EPI == 0) {
          ((unsigned short*)Cout)[idxo] = f2bf(v);
        } else if (EPI == 1) {
          ((unsigned short*)Cout)[idxo] = f2bf(v + Dvec[col] * bf2f(aux16[idxo]));
        } else {
          float z = v + Dvec[col];
          float sg = 1.f / (1.f + expf(-z));
          ((float*)Cout)[idxo] = skip[idxo] + bf2f(aux16[idxo]) * sg;
        }
      }
    }
  }
}

// ---------------- chunked scan (Bu bf16) ----------------
__global__ void scanA_kernel(const unsigned short* __restrict__ Bu, const void* __restrict__ d,
                             const int* __restrict__ dflag, const float* __restrict__ lam_re,
                             const float* __restrict__ lam_im, float* __restrict__ Ar,
                             float* __restrict__ Ai, float* __restrict__ Sr,
                             float* __restrict__ Si) {
  int bx = blockIdx.x;  // c*16 + b
  int c = bx >> 4, b = bx & 15;
  int p = threadIdx.x;
  int fl = *dflag;
  float lr = lam_re[p], li = lam_im[p];
  float Apr = 1.f, Api = 0.f, sr = 0.f, si = 0.f;
  int l0 = c * CLEN;
  for (int j = 0; j < CLEN; j++) {
    int l = l0 + j;
    float kp = keep_val(d, fl, l * BB + b);
    float ar = lr * kp, ai = li * kp;
    size_t ro = (size_t)(l * BB + b) * NN;
    float bur = bf2f(Bu[ro + p]), bui = bf2f(Bu[ro + PP + p]);
    float nsr = ar * sr - ai * si + bur;
    float nsi = ar * si + ai * sr + bui;
    sr = nsr; si = nsi;
    float nar = ar * Apr - ai * Api;
    float nai = ar * Api + ai * Apr;
    Apr = nar; Api = nai;
  }
  int o = bx * PP + p;
  Ar[o] = Apr; Ai[o] = Api; Sr[o] = sr; Si[o] = si;
}

__global__ void scanB_kernel(const float* __restrict__ hr0, const float* __restrict__ hi0,
                             const float* __restrict__ Ar, const float* __restrict__ Ai,
                             const float* __restrict__ Sr, const float* __restrict__ Si,
                             float* __restrict__ Cr, float* __restrict__ Ci,
                             float* __restrict__ outHid) {
  int b = blockIdx.x;
  int p = threadIdx.x;
  float cr = hr0[b * PP + p], ci = hi0[b * PP + p];
  for (int c = 0; c < NC; c++) {
    int o = (c * BB + b) * PP + p;
    Cr[o] = cr; Ci[o] = ci;
    float ar = Ar[o], ai = Ai[o];
    float nr = ar * cr - ai * ci + Sr[o];
    float ni = ar * ci + ai * cr + Si[o];
    cr = nr; ci = ni;
  }
  outHid[b * PP + p] = cr;                 // new_hidden.real
  outHid[BB * PP + b * PP + p] = ci;       // new_hidden.imag
}

__global__ void scanC_kernel(const unsigned short* __restrict__ Bu, const void* __restrict__ d,
                             const int* __restrict__ dflag, const float* __restrict__ lam_re,
                             const float* __restrict__ lam_im, const float* __restrict__ Cr,
                             const float* __restrict__ Ci, unsigned short* __restrict__ xs) {
  int bx = blockIdx.x;
  int c = bx >> 4, b = bx & 15;
  int p = threadIdx.x;
  int fl = *dflag;
  float lr = lam_re[p], li = lam_im[p];
  float hr = Cr[bx * PP + p], hi = Ci[bx * PP + p];
  int l0 = c * CLEN;
  for (int j = 0; j < CLEN; j++) {
    int l = l0 + j;
    float kp = keep_val(d, fl, l * BB + b);
    float ar = lr * kp, ai = li * kp;
    size_t ro = (size_t)(l * BB + b) * NN;
    float bur = bf2f(Bu[ro + p]), bui = bf2f(Bu[ro + PP + p]);
    float nhr = ar * hr - ai * hi + bur;
    float nhi = ar * hi + ai * hr + bui;
    hr = nhr; hi = nhi;
    xs[ro + p] = f2bf(hr);
    xs[ro + PP + p] = f2bf(hi);
  }
}

// ---------------- launcher ----------------
extern "C" void kernel_launch(void* const* d_in, const int* in_sizes, int n_in,
                              void* d_out, int out_size, void* d_ws, size_t ws_size,
                              hipStream_t stream) {
  const float* x    = (const float*)d_in[0];
  const void*  dmask= d_in[1];
  const float* hidr = (const float*)d_in[2];
  const float* hidi = (const float*)d_in[3];
  const float* Lre  = (const float*)d_in[4];
  const float* Lim  = (const float*)d_in[5];
  const float* Bre  = (const float*)d_in[6];
  const float* Bim  = (const float*)d_in[7];
  const float* Cre  = (const float*)d_in[8];
  const float* Cim  = (const float*)d_in[9];
  const float* Dv   = (const float*)d_in[10];
  const float* lst  = (const float*)d_in[11];
  const float* lsc  = (const float*)d_in[12];
  const float* lbs  = (const float*)d_in[13];
  const float* w2   = (const float*)d_in[14];
  const float* b2   = (const float*)d_in[15];
  float* out = (float*)d_out;

  char* ws = (char*)d_ws;
  size_t off = 0;
  auto alloc = [&](size_t bytes) -> void* {
    void* p = ws + off;
    off += (bytes + 255) & ~(size_t)255;
    return p;
  };
  unsigned short* xn  = (unsigned short*)alloc((size_t)MM * KK * 2);  // 32MB; reused as y
  unsigned short* xs  = (unsigned short*)alloc((size_t)MM * KK * 2);  // 32MB; reused as x1
  unsigned short* Bu  = (unsigned short*)alloc((size_t)MM * NN * 2);  // 32MB bf16; reused as ys
  unsigned short* W1t = (unsigned short*)alloc((size_t)NN * KK * 2);
  unsigned short* W2t = (unsigned short*)alloc((size_t)NN * KK * 2);
  unsigned short* W3t = (unsigned short*)alloc((size_t)NN * KK * 2);
  float* lam_re = (float*)alloc(PP * 4);
  float* lam_im = (float*)alloc(PP * 4);
  float* Ar = (float*)alloc((size_t)NC * BB * PP * 4);
  float* Ai = (float*)alloc((size_t)NC * BB * PP * 4);
  float* Sr = (float*)alloc((size_t)NC * BB * PP * 4);
  float* Si = (float*)alloc((size_t)NC * BB * PP * 4);
  float* Cr = (float*)alloc((size_t)NC * BB * PP * 4);
  float* Ci = (float*)alloc((size_t)NC * BB * PP * 4);
  int* dflag = (int*)alloc(256);
  unsigned short* y   = xn;   // reuse after GEMM2 consumed xn
  unsigned short* x1  = xs;   // reuse after GEMM2 consumed xs
  unsigned short* ysb = Bu;   // reuse after scan consumed Bu

  // 128KB dynamic LDS for the 8-phase GEMM
  hipFuncSetAttribute((const void*)gemm_kernel<0>,
                      hipFuncAttributeMaxDynamicSharedMemorySize, 131072);
  hipFuncSetAttribute((const void*)gemm_kernel<1>,
                      hipFuncAttributeMaxDynamicSharedMemorySize, 131072);
  hipFuncSetAttribute((const void*)gemm_kernel<2>,
                      hipFuncAttributeMaxDynamicSharedMemorySize, 131072);

  detect_kernel<<<1, 256, 0, stream>>>((const unsigned int*)dmask, dflag);
  precompute_kernel<<<1024, 256, 0, stream>>>(Lre, Lim, Bre, Bim, Cre, Cim, lst, w2,
                                              W1t, W2t, W3t, lam_re, lam_im);
  ln1_kernel<<<MM / 4, 256, 0, stream>>>(x, lsc, lbs, xn);
  gemm_kernel<0><<<256, 512, 131072, stream>>>(xn, W1t, Bu, nullptr, nullptr, nullptr);
  scanA_kernel<<<NC * BB, 256, 0, stream>>>(Bu, dmask, dflag, lam_re, lam_im, Ar, Ai, Sr, Si);
  scanB_kernel<<<BB, 256, 0, stream>>>(hidr, hidi, Ar, Ai, Sr, Si, Cr, Ci, out);
  scanC_kernel<<<NC * BB, 256, 0, stream>>>(Bu, dmask, dflag, lam_re, lam_im, Cr, Ci, xs);
  gemm_kernel<1><<<256, 512, 131072, stream>>>(xs, W2t, ysb, Dv, xn, nullptr);
  ln2_kernel<<<MM / 4, 256, 0, stream>>>(ysb, lsc, lbs, y, x1);
  gemm_kernel<2><<<256, 512, 131072, stream>>>(x1, W3t, out + 2 * BB * PP, b2, y, x);
}

// Round 5
// 196.448 us; speedup vs baseline: 1.0159x; 1.0159x over previous
//
#include <hip/hip_runtime.h>

// ---------------- problem constants ----------------
#define LL 2048
#define BB 16
#define HH 512
#define PP 256
#define MM (LL*BB)   // 32768 rows
#define NN 512       // all GEMMs: N=512
#define KK 512       // all GEMMs: K=512
#define NC 64        // scan chunks
#define CLEN 32      // chunk length (NC*CLEN == LL)
#define NKT (KK/64)  // 8 K-tiles of 64

typedef __bf16 bf16x8 __attribute__((ext_vector_type(8)));
typedef float  f32x4  __attribute__((ext_vector_type(4)));

__device__ __forceinline__ unsigned short f2bf(float f) {
  unsigned u = __builtin_bit_cast(unsigned, f);
  u = (u + 0x7fffu + ((u >> 16) & 1u)) >> 16;   // RNE
  return (unsigned short)u;
}
__device__ __forceinline__ float bf2f(unsigned short s) {
  unsigned u = ((unsigned)s) << 16;
  return __builtin_bit_cast(float, u);
}

// ---------------- dtype detection for `d` ----------------
__global__ void detect_kernel(const unsigned int* __restrict__ dw, int* __restrict__ flag) {
  __shared__ int sInt, sFloat;
  if (threadIdx.x == 0) { sInt = 1; sFloat = 1; }
  __syncthreads();
  int allInt = 1, allFloat = 1;
  for (int i = threadIdx.x; i < 8192; i += 256) {
    unsigned v = dw[i];
    if (v > 1u) allInt = 0;
    if (v != 0u && v != 0x3f800000u) allFloat = 0;
  }
  if (!allInt) atomicAnd(&sInt, 0);
  if (!allFloat) atomicAnd(&sFloat, 0);
  __syncthreads();
  if (threadIdx.x == 0) *flag = sInt ? 0 : (sFloat ? 1 : 2);
}

__device__ __forceinline__ float keep_val(const void* d, int flag, int idx) {
  if (flag == 0) return 1.f - (float)((const int*)d)[idx];
  if (flag == 1) return 1.f - ((const float*)d)[idx];
  return 1.f - (float)((const unsigned char*)d)[idx];
}

// ---------------- weight precompute ----------------
__global__ void precompute_kernel(
    const float* __restrict__ Lre, const float* __restrict__ Lim,
    const float* __restrict__ Bre, const float* __restrict__ Bim,
    const float* __restrict__ Cre, const float* __restrict__ Cim,
    const float* __restrict__ lstep, const float* __restrict__ w2,
    unsigned short* __restrict__ W1t, unsigned short* __restrict__ W2t,
    unsigned short* __restrict__ W3t, float* __restrict__ lam_re,
    float* __restrict__ lam_im) {
  int t = blockIdx.x * 256 + threadIdx.x;   // 0..262143
  int k = t & (KK - 1);
  int n = t >> 9;
  {
    int p = n & (PP - 1);
    float lr = Lre[p], li = Lim[p];
    float st = expf(lstep[p]);
    float er = expf(lr * st);
    float ang = li * st;
    float lbr = er * cosf(ang), lbi = er * sinf(ang);
    float den = lr * lr + li * li;
    float wr = ((lbr - 1.f) * lr + lbi * li) / den;
    float wi = (lbi * lr - (lbr - 1.f) * li) / den;
    float br = Bre[p * HH + k], bi = Bim[p * HH + k];
    float v = (n < PP) ? (wr * br - wi * bi) : (wr * bi + wi * br);
    W1t[(size_t)n * KK + k] = f2bf(v);
  }
  {
    float v = (k < PP) ? (2.f * Cre[n * PP + k]) : (-2.f * Cim[n * PP + (k - PP)]);
    W2t[(size_t)n * KK + k] = f2bf(v);
  }
  W3t[(size_t)n * KK + k] = f2bf(w2[(size_t)k * HH + n]);
  if (t < PP) {
    float lr = Lre[t], li = Lim[t];
    float st = expf(lstep[t]);
    float er = expf(lr * st);
    float ang = li * st;
    lam_re[t] = er * cosf(ang);
    lam_im[t] = er * sinf(ang);
  }
}

// ---------------- LayerNorm (1 wave per 512-wide row, 4 rows/block) -------------
__global__ void ln1_kernel(const float* __restrict__ x, const float* __restrict__ sc,
                           const float* __restrict__ bs, unsigned short* __restrict__ xn) {
  int row = blockIdx.x * 4 + (threadIdx.x >> 6);
  int lane = threadIdx.x & 63;
  const float4* xr = (const float4*)(x + (size_t)row * HH) + lane * 2;
  float4 a = xr[0], b = xr[1];
  float s = (a.x + a.y) + (a.z + a.w) + (b.x + b.y) + (b.z + b.w);
  float q = a.x * a.x + a.y * a.y + a.z * a.z + a.w * a.w +
            b.x * b.x + b.y * b.y + b.z * b.z + b.w * b.w;
#pragma unroll
  for (int off = 32; off; off >>= 1) { s += __shfl_xor(s, off); q += __shfl_xor(q, off); }
  float mean = s * (1.f / HH);
  float var = fmaxf(q * (1.f / HH) - mean * mean, 0.f);
  float rstd = rsqrtf(var + 1e-6f);
  const float4* scp = (const float4*)sc + lane * 2;
  const float4* bsp = (const float4*)bs + lane * 2;
  float4 s0 = scp[0], s1 = scp[1], b0 = bsp[0], b1 = bsp[1];
  unsigned short o[8];
  o[0] = f2bf((a.x - mean) * rstd * s0.x + b0.x);
  o[1] = f2bf((a.y - mean) * rstd * s0.y + b0.y);
  o[2] = f2bf((a.z - mean) * rstd * s0.z + b0.z);
  o[3] = f2bf((a.w - mean) * rstd * s0.w + b0.w);
  o[4] = f2bf((b.x - mean) * rstd * s1.x + b1.x);
  o[5] = f2bf((b.y - mean) * rstd * s1.y + b1.y);
  o[6] = f2bf((b.z - mean) * rstd * s1.z + b1.z);
  o[7] = f2bf((b.w - mean) * rstd * s1.w + b1.w);
  uint4 pk;
  pk.x = o[0] | ((unsigned)o[1] << 16);
  pk.y = o[2] | ((unsigned)o[3] << 16);
  pk.z = o[4] | ((unsigned)o[5] << 16);
  pk.w = o[6] | ((unsigned)o[7] << 16);
  *((uint4*)(xn + (size_t)row * HH) + lane) = pk;
}

// LN + GELU: reads ys (bf16), writes y (bf16) and x1 = gelu(y) (bf16)
__global__ void ln2_kernel(const unsigned short* __restrict__ ys, const float* __restrict__ sc,
                           const float* __restrict__ bs, unsigned short* __restrict__ y,
                           unsigned short* __restrict__ x1) {
  int row = blockIdx.x * 4 + (threadIdx.x >> 6);
  int lane = threadIdx.x & 63;
  uint4 pin = *((const uint4*)(ys + (size_t)row * HH) + lane);
  float v[8];
  v[0] = bf2f((unsigned short)(pin.x & 0xffff)); v[1] = bf2f((unsigned short)(pin.x >> 16));
  v[2] = bf2f((unsigned short)(pin.y & 0xffff)); v[3] = bf2f((unsigned short)(pin.y >> 16));
  v[4] = bf2f((unsigned short)(pin.z & 0xffff)); v[5] = bf2f((unsigned short)(pin.z >> 16));
  v[6] = bf2f((unsigned short)(pin.w & 0xffff)); v[7] = bf2f((unsigned short)(pin.w >> 16));
  float s = 0.f, q = 0.f;
#pragma unroll
  for (int j = 0; j < 8; j++) { s += v[j]; q += v[j] * v[j]; }
#pragma unroll
  for (int off = 32; off; off >>= 1) { s += __shfl_xor(s, off); q += __shfl_xor(q, off); }
  float mean = s * (1.f / HH);
  float var = fmaxf(q * (1.f / HH) - mean * mean, 0.f);
  float rstd = rsqrtf(var + 1e-6f);
  const float4* scp = (const float4*)sc + lane * 2;
  const float4* bsp = (const float4*)bs + lane * 2;
  float4 s0 = scp[0], s1 = scp[1], b0 = bsp[0], b1 = bsp[1];
  float scv[8] = { s0.x, s0.y, s0.z, s0.w, s1.x, s1.y, s1.z, s1.w };
  float bsv[8] = { b0.x, b0.y, b0.z, b0.w, b1.x, b1.y, b1.z, b1.w };
  unsigned short oy[8], og[8];
#pragma unroll
  for (int j = 0; j < 8; j++) {
    float yv = (v[j] - mean) * rstd * scv[j] + bsv[j];
    oy[j] = f2bf(yv);
    float g = 0.5f * yv * (1.f + tanhf(0.7978845608f * (yv + 0.044715f * yv * yv * yv)));
    og[j] = f2bf(g);
  }
  uint4 py, pg;
  py.x = oy[0] | ((unsigned)oy[1] << 16); py.y = oy[2] | ((unsigned)oy[3] << 16);
  py.z = oy[4] | ((unsigned)oy[5] << 16); py.w = oy[6] | ((unsigned)oy[7] << 16);
  pg.x = og[0] | ((unsigned)og[1] << 16); pg.y = og[2] | ((unsigned)og[3] << 16);
  pg.z = og[4] | ((unsigned)og[5] << 16); pg.w = og[6] | ((unsigned)og[7] << 16);
  *((uint4*)(y  + (size_t)row * HH) + lane) = py;
  *((uint4*)(x1 + (size_t)row * HH) + lane) = pg;
}

// ============ V2: 256x256 8-phase GEMM (EPI 0 only) + LDS-bounce epilogue ============
template <int EPI>
__global__ __launch_bounds__(512, 2) void gemm256_kernel(
    const unsigned short* __restrict__ A, const unsigned short* __restrict__ Wt,
    void* __restrict__ Cout, const float* __restrict__ Dvec,
    const unsigned short* __restrict__ aux16, const float* __restrict__ skip) {
  extern __shared__ unsigned short smem[];   // 128KB
  const int tid = threadIdx.x;
  const int w = tid >> 6, lane = tid & 63;
  const int wr = w >> 2, wc = w & 3;         // 2 x 4 wave grid
  const int l15 = lane & 15, g16 = lane >> 4;
  const int wgid = blockIdx.x;
  const int xcd = wgid & 7, bidx = wgid >> 3;       // bidx 0..31
  const int m0 = (xcd * 16 + (bidx >> 1)) * 256;
  const int n0 = (bidx & 1) * 256;

  const int rS = tid >> 2;
  const int cgS = (tid & 3) ^ ((rS >> 1) & 3);

  auto stageA = [&](int buf, int kh, int kt) {
    const unsigned short* gp = A + (size_t)(m0 + rS) * KK + kt * 64 + kh * 32 + cgS * 8;
    unsigned short* dp = smem + buf * 16384 + kh * 8192 + (w * 64) * 8;
    __builtin_amdgcn_global_load_lds((const __attribute__((address_space(1))) void*)gp,
                                     (__attribute__((address_space(3))) void*)dp, 16, 0, 0);
    __builtin_amdgcn_global_load_lds(
        (const __attribute__((address_space(1))) void*)(gp + (size_t)128 * KK),
        (__attribute__((address_space(3))) void*)(dp + 512 * 8), 16, 0, 0);
  };
  auto stageB = [&](int buf, int kh, int kt) {
    const unsigned short* gp = Wt + (size_t)(n0 + rS) * KK + kt * 64 + kh * 32 + cgS * 8;
    unsigned short* dp = smem + 32768 + buf * 16384 + kh * 8192 + (w * 64) * 8;
    __builtin_amdgcn_global_load_lds((const __attribute__((address_space(1))) void*)gp,
                                     (__attribute__((address_space(3))) void*)dp, 16, 0, 0);
    __builtin_amdgcn_global_load_lds(
        (const __attribute__((address_space(1))) void*)(gp + (size_t)128 * KK),
        (__attribute__((address_space(3))) void*)(dp + 512 * 8), 16, 0, 0);
  };
  auto readA = [&](int buf, int ks, int fm) -> bf16x8 {
    int row = wr * 128 + fm * 16 + l15;
    int ch = g16 ^ ((row >> 1) & 3);
    return *(const bf16x8*)(smem + buf * 16384 + ks * 8192 + row * 32 + ch * 8);
  };
  auto readB = [&](int buf, int ks, int fn) -> bf16x8 {
    int row = wc * 64 + fn * 16 + l15;
    int ch = g16 ^ ((row >> 1) & 3);
    return *(const bf16x8*)(smem + 32768 + buf * 16384 + ks * 8192 + row * 32 + ch * 8);
  };

  f32x4 acc[8][4];
#pragma unroll
  for (int i = 0; i < 8; i++)
#pragma unroll
    for (int j = 0; j < 4; j++) acc[i][j] = (f32x4){0.f, 0.f, 0.f, 0.f};
  bf16x8 bF[4];

#define PHASE(CB, KS, FG, STAGE_STMT, DO_VM)                                    \
  {                                                                             \
    bf16x8 aF[4];                                                               \
    _Pragma("unroll") for (int fi = 0; fi < 4; fi++)                            \
        aF[fi] = readA(CB, KS, (FG)*4 + fi);                                    \
    if ((FG) == 0) {                                                            \
      _Pragma("unroll") for (int fi = 0; fi < 4; fi++) bF[fi] = readB(CB, KS, fi); \
    }                                                                           \
    STAGE_STMT;                                                                 \
    __builtin_amdgcn_s_barrier();                                               \
    asm volatile("s_waitcnt lgkmcnt(0)" ::: "memory");                          \
    __builtin_amdgcn_s_setprio(1);                                              \
    _Pragma("unroll") for (int fi = 0; fi < 4; fi++)                            \
      _Pragma("unroll") for (int fj = 0; fj < 4; fj++)                          \
        acc[(FG)*4 + fi][fj] = __builtin_amdgcn_mfma_f32_16x16x32_bf16(         \
            aF[fi], bF[fj], acc[(FG)*4 + fi][fj], 0, 0, 0);                     \
    __builtin_amdgcn_s_setprio(0);                                              \
    if (DO_VM) asm volatile("s_waitcnt vmcnt(8)" ::: "memory");                 \
    __builtin_amdgcn_s_barrier();                                               \
  }

  stageA(0, 0, 0); stageB(0, 0, 0);
  stageA(0, 1, 0); stageB(0, 1, 0);
  stageA(1, 0, 1); stageB(1, 0, 1);
  asm volatile("s_waitcnt vmcnt(8)" ::: "memory");
  __builtin_amdgcn_s_barrier();

  for (int j = 0; j < NKT / 2; ++j) {
    const int t1 = 2 * j + 1;
    const int t2 = (2 * j + 2 < NKT) ? 2 * j + 2 : NKT - 1;
    const int t3 = (2 * j + 3 < NKT) ? 2 * j + 3 : NKT - 1;
    const bool s2 = (2 * j + 2) < NKT, s3 = (2 * j + 3) < NKT;
    PHASE(0, 0, 0, { stageA(1, 1, t1); }, false);
    PHASE(0, 0, 1, { stageB(1, 1, t1); }, true);
    PHASE(0, 1, 0, { if (s2) stageA(0, 0, t2); }, false);
    PHASE(0, 1, 1, { if (s2) stageB(0, 0, t2); }, true);
    PHASE(1, 0, 0, { if (s2) stageA(0, 1, t2); }, false);
    PHASE(1, 0, 1, { if (s2) stageB(0, 1, t2); }, true);
    PHASE(1, 1, 0, { if (s3) stageA(1, 0, t3); }, false);
    PHASE(1, 1, 1, { if (s3) stageB(1, 0, t3); }, true);
  }
#undef PHASE

  // ---- LDS-bounce epilogue: 4 chunks of 64 rows, 512B-contiguous stores ----
  __syncthreads();                       // drain any残 vmcnt + guard LDS reuse
  unsigned short* lbf = smem;            // [64][264] bf16 (row stride 528B)
#pragma unroll
  for (int j = 0; j < 4; j++) {
#pragma unroll
    for (int h = 0; h < 2; h++) {        // fm = 2j+h
      int fm = 2 * j + h;
#pragma unroll
      for (int fn = 0; fn < 4; fn++) {
        int col = wc * 64 + fn * 16 + l15;
#pragma unroll
        for (int jj = 0; jj < 4; jj++) {
          int lrow = wr * 32 + h * 16 + g16 * 4 + jj;
          lbf[lrow * 264 + col] = f2bf(acc[fm][fn][jj]);
        }
      }
    }
    __syncthreads();
    // stream out: 64 rows x 512B; 4 sweeps x (16 rows x 32 lanes x 16B)
#pragma unroll
    for (int sw = 0; sw < 4; sw++) {
      int lrow = sw * 16 + (tid >> 5);
      int tc = tid & 31;
      int grow = m0 + (lrow >> 5) * 128 + (2 * j + ((lrow >> 4) & 1)) * 16 + (lrow & 15);
      int gcol = n0 + tc * 8;
      uint4 v = *(const uint4*)&lbf[lrow * 264 + tc * 8];
      *(uint4*)(((unsigned short*)Cout) + (size_t)grow * NN + gcol) = v;
    }
    __syncthreads();
  }
}

// ============ V1: 128x128 simple 2-barrier GEMM, 4 blocks/CU + LDS-bounce ============
// EPI 1: C = acc + Dvec[col]*bf(aux16)   (bf16 out)
// EPI 2: C = skip + bf(aux16)*sigmoid(acc + Dvec[col])   (f32 out)
template <int EPI>
__global__ __launch_bounds__(256, 4) void gemm128_kernel(
    const unsigned short* __restrict__ A, const unsigned short* __restrict__ Wt,
    void* __restrict__ Cout, const float* __restrict__ Dvec,
    const unsigned short* __restrict__ aux16, const float* __restrict__ skip) {
  __shared__ char lds[33280];
  unsigned short* lA = (unsigned short*)lds;            // [128][64]
  unsigned short* lB = (unsigned short*)(lds + 16384);  // [128][64]
  int tid = threadIdx.x;
  int w = tid >> 6, lane = tid & 63;
  int wgid = blockIdx.x;
  int xcd = wgid & 7, bidx = wgid >> 3;          // bidx 0..127
  int m0 = (xcd * 32 + (bidx >> 2)) * 128;
  int n0 = (bidx & 3) * 128;
  int wr = w >> 1, wc = w & 1;
  const int l15 = lane & 15, g16 = lane >> 4;
  f32x4 acc[4][4];
#pragma unroll
  for (int i = 0; i < 4; i++)
#pragma unroll
    for (int j = 0; j < 4; j++) acc[i][j] = (f32x4){0.f, 0.f, 0.f, 0.f};

  for (int kt = 0; kt < NKT; ++kt) {
    __syncthreads();
#pragma unroll
    for (int i = 0; i < 4; i++) {
      int sidx = i * 256 + tid;
      int r = sidx >> 3, c = sidx & 7;
      int cs = c ^ (r & 7);
      const unsigned short* g = A + (size_t)(m0 + r) * KK + kt * 64 + cs * 8;
      unsigned short* l = &lA[(i * 256 + w * 64) * 8];
      __builtin_amdgcn_global_load_lds((const __attribute__((address_space(1))) void*)g,
                                       (__attribute__((address_space(3))) void*)l, 16, 0, 0);
    }
#pragma unroll
    for (int i = 0; i < 4; i++) {
      int sidx = i * 256 + tid;
      int r = sidx >> 3, c = sidx & 7;
      int cs = c ^ (r & 7);
      const unsigned short* g = Wt + (size_t)(n0 + r) * KK + kt * 64 + cs * 8;
      unsigned short* l = &lB[(i * 256 + w * 64) * 8];
      __builtin_amdgcn_global_load_lds((const __attribute__((address_space(1))) void*)g,
                                       (__attribute__((address_space(3))) void*)l, 16, 0, 0);
    }
    __syncthreads();
#pragma unroll
    for (int ks = 0; ks < 2; ++ks) {
      bf16x8 aF[4], bF[4];
#pragma unroll
      for (int m = 0; m < 4; m++) {
        int row = wr * 64 + m * 16 + l15;
        int s = ks * 4 + g16;
        aF[m] = *(const bf16x8*)&lA[row * 64 + (s ^ (row & 7)) * 8];
      }
#pragma unroll
      for (int n = 0; n < 4; n++) {
        int row = wc * 64 + n * 16 + l15;
        int s = ks * 4 + g16;
        bF[n] = *(const bf16x8*)&lB[row * 64 + (s ^ (row & 7)) * 8];
      }
#pragma unroll
      for (int m = 0; m < 4; m++)
#pragma unroll
        for (int n = 0; n < 4; n++)
          acc[m][n] = __builtin_amdgcn_mfma_f32_16x16x32_bf16(aF[m], bF[n], acc[m][n], 0, 0, 0);
    }
  }
  __syncthreads();

  // ---- LDS-bounce epilogue: 4 chunks (fm=j), 32 rows each ----
  if (EPI == 1) {
    unsigned short* lbf = (unsigned short*)lds;   // [32][136]
#pragma unroll
    for (int j = 0; j < 4; j++) {
#pragma unroll
      for (int fn = 0; fn < 4; fn++) {
        int col = wc * 64 + fn * 16 + l15;
#pragma unroll
        for (int jj = 0; jj < 4; jj++) {
          int lrow = wr * 16 + g16 * 4 + jj;
          lbf[lrow * 136 + col] = f2bf(acc[j][fn][jj]);
        }
      }
      __syncthreads();
#pragma unroll
      for (int sw = 0; sw < 2; sw++) {
        int lrow = sw * 16 + (tid >> 4);
        int tc = tid & 15;
        int grow = m0 + (lrow >> 4) * 64 + j * 16 + (lrow & 15);
        int gcol = n0 + tc * 8;
        uint4 v = *(const uint4*)&lbf[lrow * 136 + tc * 8];
        uint4 au = *(const uint4*)(aux16 + (size_t)grow * NN + gcol);
        float4 d0 = *(const float4*)&Dvec[gcol];
        float4 d1 = *(const float4*)&Dvec[gcol + 4];
        unsigned short o[8];
        unsigned vv[4] = { v.x, v.y, v.z, v.w };
        unsigned aa[4] = { au.x, au.y, au.z, au.w };
        float dd[8] = { d0.x, d0.y, d0.z, d0.w, d1.x, d1.y, d1.z, d1.w };
#pragma unroll
        for (int e = 0; e < 8; e++) {
          float av = bf2f((unsigned short)((e & 1) ? (vv[e >> 1] >> 16) : (vv[e >> 1] & 0xffff)));
          float xu = bf2f((unsigned short)((e & 1) ? (aa[e >> 1] >> 16) : (aa[e >> 1] & 0xffff)));
          o[e] = f2bf(av + dd[e] * xu);
        }
        uint4 pk;
        pk.x = o[0] | ((unsigned)o[1] << 16); pk.y = o[2] | ((unsigned)o[3] << 16);
        pk.z = o[4] | ((unsigned)o[5] << 16); pk.w = o[6] | ((unsigned)o[7] << 16);
        *(uint4*)(((unsigned short*)Cout) + (size_t)grow * NN + gcol) = pk;
      }
      __syncthreads();
    }
  } else {   // EPI == 2
    float* lf = (float*)lds;                       // [32][132]
#pragma unroll
    for (int j = 0; j < 4; j++) {
#pragma unroll
      for (int fn = 0; fn < 4; fn++) {
        int col = wc * 64 + fn * 16 + l15;
#pragma unroll
        for (int jj = 0; jj < 4; jj++) {
          int lrow = wr * 16 + g16 * 4 + jj;
          lf[lrow * 132 + col] = acc[j][fn][jj];
        }
      }
      __syncthreads();
#pragma unroll
      for (int sw = 0; sw < 4; sw++) {
        int lrow = sw * 8 + (tid >> 5);
        int tc = tid & 31;
        int grow = m0 + (lrow >> 4) * 64 + j * 16 + (lrow & 15);
        int gcol = n0 + tc * 4;
        float4 v = *(const float4*)&lf[lrow * 132 + tc * 4];
        float4 d = *(const float4*)&Dvec[gcol];
        float4 sk = *(const float4*)(skip + (size_t)grow * NN + gcol);
        ushort4 au = *(const ushort4*)(aux16 + (size_t)grow * NN + gcol);
        float4 o;
        o.x = sk.x + bf2f(au.x) / (1.f + expf(-(v.x + d.x)));
        o.y = sk.y + bf2f(au.y) / (1.f + expf(-(v.y + d.y)));
        o.z = sk.z + bf2f(au.z) / (1.f + expf(-(v.z + d.z)));
        o.w = sk.w + bf2f(au.w) / (1.f + expf(-(v.w + d.w)));
        *(float4*)(((float*)Cout) + (size_t)grow * NN + gcol) = o;
      }
      __syncthreads();
    }
  }
}

// ---------------- chunked scan (Bu bf16) ----------------
__global__ void scanA_kernel(const unsigned short* __restrict__ Bu, const void* __restrict__ d,
                             const int* __restrict__ dflag, const float* __restrict__ lam_re,
                             const float* __restrict__ lam_im, float* __restrict__ Ar,
                             float* __restrict__ Ai, float* __restrict__ Sr,
                             float* __restrict__ Si) {
  int bx = blockIdx.x;  // c*16 + b
  int c = bx >> 4, b = bx & 15;
  int p = threadIdx.x;
  int fl = *dflag;
  float lr = lam_re[p], li = lam_im[p];
  float Apr = 1.f, Api = 0.f, sr = 0.f, si = 0.f;
  int l0 = c * CLEN;
  for (int j = 0; j < CLEN; j++) {
    int l = l0 + j;
    float kp = keep_val(d, fl, l * BB + b);
    float ar = lr * kp, ai = li * kp;
    size_t ro = (size_t)(l * BB + b) * NN;
    float bur = bf2f(Bu[ro + p]), bui = bf2f(Bu[ro + PP + p]);
    float nsr = ar * sr - ai * si + bur;
    float nsi = ar * si + ai * sr + bui;
    sr = nsr; si = nsi;
    float nar = ar * Apr - ai * Api;
    float nai = ar * Api + ai * Apr;
    Apr = nar; Api = nai;
  }
  int o = bx * PP + p;
  Ar[o] = Apr; Ai[o] = Api; Sr[o] = sr; Si[o] = si;
}

__global__ void scanB_kernel(const float* __restrict__ hr0, const float* __restrict__ hi0,
                             const float* __restrict__ Ar, const float* __restrict__ Ai,
                             const float* __restrict__ Sr, const float* __restrict__ Si,
                             float* __restrict__ Cr, float* __restrict__ Ci,
                             float* __restrict__ outHid) {
  int b = blockIdx.x;
  int p = threadIdx.x;
  float cr = hr0[b * PP + p], ci = hi0[b * PP + p];
  for (int c = 0; c < NC; c++) {
    int o = (c * BB + b) * PP + p;
    Cr[o] = cr; Ci[o] = ci;
    float ar = Ar[o], ai = Ai[o];
    float nr = ar * cr - ai * ci + Sr[o];
    float ni = ar * ci + ai * cr + Si[o];
    cr = nr; ci = ni;
  }
  outHid[b * PP + p] = cr;                 // new_hidden.real
  outHid[BB * PP + b * PP + p] = ci;       // new_hidden.imag
}

__global__ void scanC_kernel(const unsigned short* __restrict__ Bu, const void* __restrict__ d,
                             const int* __restrict__ dflag, const float* __restrict__ lam_re,
                             const float* __restrict__ lam_im, const float* __restrict__ Cr,
                             const float* __restrict__ Ci, unsigned short* __restrict__ xs) {
  int bx = blockIdx.x;
  int c = bx >> 4, b = bx & 15;
  int p = threadIdx.x;
  int fl = *dflag;
  float lr = lam_re[p], li = lam_im[p];
  float hr = Cr[bx * PP + p], hi = Ci[bx * PP + p];
  int l0 = c * CLEN;
  for (int j = 0; j < CLEN; j++) {
    int l = l0 + j;
    float kp = keep_val(d, fl, l * BB + b);
    float ar = lr * kp, ai = li * kp;
    size_t ro = (size_t)(l * BB + b) * NN;
    float bur = bf2f(Bu[ro + p]), bui = bf2f(Bu[ro + PP + p]);
    float nhr = ar * hr - ai * hi + bur;
    float nhi = ar * hi + ai * hr + bui;
    hr = nhr; hi = nhi;
    xs[ro + p] = f2bf(hr);
    xs[ro + PP + p] = f2bf(hi);
  }
}

// ---------------- launcher ----------------
extern "C" void kernel_launch(void* const* d_in, const int* in_sizes, int n_in,
                              void* d_out, int out_size, void* d_ws, size_t ws_size,
                              hipStream_t stream) {
  const float* x    = (const float*)d_in[0];
  const void*  dmask= d_in[1];
  const float* hidr = (const float*)d_in[2];
  const float* hidi = (const float*)d_in[3];
  const float* Lre  = (const float*)d_in[4];
  const float* Lim  = (const float*)d_in[5];
  const float* Bre  = (const float*)d_in[6];
  const float* Bim  = (const float*)d_in[7];
  const float* Cre  = (const float*)d_in[8];
  const float* Cim  = (const float*)d_in[9];
  const float* Dv   = (const float*)d_in[10];
  const float* lst  = (const float*)d_in[11];
  const float* lsc  = (const float*)d_in[12];
  const float* lbs  = (const float*)d_in[13];
  const float* w2   = (const float*)d_in[14];
  const float* b2   = (const float*)d_in[15];
  float* out = (float*)d_out;

  char* ws = (char*)d_ws;
  size_t off = 0;
  auto alloc = [&](size_t bytes) -> void* {
    void* p = ws + off;
    off += (bytes + 255) & ~(size_t)255;
    return p;
  };
  unsigned short* xn  = (unsigned short*)alloc((size_t)MM * KK * 2);  // 32MB; reused as y
  unsigned short* xs  = (unsigned short*)alloc((size_t)MM * KK * 2);  // 32MB; reused as x1
  unsigned short* Bu  = (unsigned short*)alloc((size_t)MM * NN * 2);  // 32MB bf16; reused as ys
  unsigned short* W1t = (unsigned short*)alloc((size_t)NN * KK * 2);
  unsigned short* W2t = (unsigned short*)alloc((size_t)NN * KK * 2);
  unsigned short* W3t = (unsigned short*)alloc((size_t)NN * KK * 2);
  float* lam_re = (float*)alloc(PP * 4);
  float* lam_im = (float*)alloc(PP * 4);
  float* Ar = (float*)alloc((size_t)NC * BB * PP * 4);
  float* Ai = (float*)alloc((size_t)NC * BB * PP * 4);
  float* Sr = (float*)alloc((size_t)NC * BB * PP * 4);
  float* Si = (float*)alloc((size_t)NC * BB * PP * 4);
  float* Cr = (float*)alloc((size_t)NC * BB * PP * 4);
  float* Ci = (float*)alloc((size_t)NC * BB * PP * 4);
  int* dflag = (int*)alloc(256);
  unsigned short* y   = xn;   // reuse after GEMM2 consumed xn
  unsigned short* x1  = xs;   // reuse after GEMM2 consumed xs
  unsigned short* ysb = Bu;   // reuse after scan consumed Bu

  hipFuncSetAttribute((const void*)gemm256_kernel<0>,
                      hipFuncAttributeMaxDynamicSharedMemorySize, 131072);

  detect_kernel<<<1, 256, 0, stream>>>((const unsigned int*)dmask, dflag);
  precompute_kernel<<<1024, 256, 0, stream>>>(Lre, Lim, Bre, Bim, Cre, Cim, lst, w2,
                                              W1t, W2t, W3t, lam_re, lam_im);
  ln1_kernel<<<MM / 4, 256, 0, stream>>>(x, lsc, lbs, xn);
  gemm256_kernel<0><<<256, 512, 131072, stream>>>(xn, W1t, Bu, nullptr, nullptr, nullptr);
  scanA_kernel<<<NC * BB, 256, 0, stream>>>(Bu, dmask, dflag, lam_re, lam_im, Ar, Ai, Sr, Si);
  scanB_kernel<<<BB, 256, 0, stream>>>(hidr, hidi, Ar, Ai, Sr, Si, Cr, Ci, out);
  scanC_kernel<<<NC * BB, 256, 0, stream>>>(Bu, dmask, dflag, lam_re, lam_im, Cr, Ci, xs);
  gemm128_kernel<1><<<1024, 256, 0, stream>>>(xs, W2t, ysb, Dv, xn, nullptr);
  ln2_kernel<<<MM / 4, 256, 0, stream>>>(ysb, lsc, lbs, y, x1);
  gemm128_kernel<2><<<1024, 256, 0, stream>>>(x1, W3t, out + 2 * BB * PP, b2, y, x);
}